// Round 5
// baseline (528.627 us; speedup 1.0000x reference)
//
#include <hip/hip_runtime.h>

#define B_  32
#define TK_ 8192
#define H_  256
#define SR  32    // subtile rows
#define NS  4     // subtiles per block
#define NBX 64    // blocks along t (NBX*NS*SR = 8192)

typedef __bf16 bf16_t;
typedef __bf16 bf16x4 __attribute__((ext_vector_type(4)));
typedef __bf16 bf16x8 __attribute__((ext_vector_type(8)));
typedef float  floatx4 __attribute__((ext_vector_type(4)));

__device__ __forceinline__ float tanh_fast(float x) {
    // tanh(x) = 1 - 2/(1+e^{2x});  e^{2x} = exp2(2*log2(e)*x)
    float e = __builtin_amdgcn_exp2f(x * 2.885390081777927f);
    return 1.0f - 2.0f * __builtin_amdgcn_rcpf(e + 1.0f);
}

// ---------------- prep: convert We->bf16, compute dec_fea ---------------------
__global__ void prep_kernel(const float* __restrict__ s_t_hat,
                            const float* __restrict__ We,
                            const float* __restrict__ Wd,
                            const float* __restrict__ bd,
                            bf16_t* __restrict__ We_bf,
                            float* __restrict__ dec_ws) {
    int tid = threadIdx.x, blk = blockIdx.x;
    int gid = blk * 256 + tid;              // grid = 256 blocks -> 65536 threads
    We_bf[gid] = (bf16_t)We[gid];           // H*H = 65536 exactly

    if (blk >= 32 && blk < 160) {           // 32768 threads: 4 per (b,i)
        int idx  = (blk - 32) * 256 + tid;
        int pair = idx >> 2, q = idx & 3;
        int b = pair >> 8, i = pair & 255;
        const float4* sp = (const float4*)(s_t_hat + b * 2 * H_ + q * 128);
        const float4* wp = (const float4*)(Wd + (size_t)i * 2 * H_ + q * 128);
        float sum = 0.f;
        #pragma unroll 8
        for (int ii = 0; ii < 32; ++ii) {
            float4 a = sp[ii], w = wp[ii];
            sum += a.x * w.x + a.y * w.y + a.z * w.z + a.w * w.w;
        }
        sum += __shfl_xor(sum, 1, 64);
        sum += __shfl_xor(sum, 2, 64);
        if (q == 0) dec_ws[pair] = sum + bd[i];
    }
}

// ---------------- main fused pass: 32-row subtiles, LDS double-buffer ---------
// Rounds 2-4 proved: at (256,4) the allocator gets only 64 arch VGPRs and ANY
// staging held across the GEMM spills to scratch (97-211 MB of HBM writes).
// Fix: (256,3) -> ~170 regs/wave, prefetch hoisting becomes free. Grid reshaped
// to 2048 blocks of 128 rows so the 3-blocks/CU tail stays ~89% utilized.
__global__ __launch_bounds__(256, 3) void attn_main(
    const float* __restrict__ enc,
    const float* __restrict__ mask,
    const float* __restrict__ cov,
    const float* __restrict__ wc,
    const float* __restrict__ v,
    const bf16_t* __restrict__ We_bf,
    const float* __restrict__ dec_ws,
    float* __restrict__ ctx_part,   // [B][NBX][H]
    float* __restrict__ D_part,     // [B][NBX]
    float* __restrict__ attn_out) {

    __shared__ __align__(16) bf16_t As[2][SR * 264];   // ping-pong, 33792 B
    __shared__ float sp[4][SR];                        // per-wave score partials
    __shared__ float ctxp[4][256];                     // final ctx reduce
    __shared__ float cov_s[NS * SR], mask_s[NS * SR];  // whole-block cov/mask

    const int tid  = threadIdx.x;
    const int b    = blockIdx.y;
    const int xb   = blockIdx.x;
    const int lane = tid & 63, w = tid >> 6;
    const int l15  = lane & 15, l4 = lane >> 4;
    const int t0b  = xb * (NS * SR);

    // B-side per-thread constants (L2-resident)
    const int wbase = w * 64;
    float decv[4], wcv[4], vv[4];
    #pragma unroll
    for (int ni = 0; ni < 4; ++ni) {
        int g = wbase + ni * 16 + l15;
        decv[ni] = dec_ws[b * H_ + g];
        wcv[ni]  = wc[g];
        vv[ni]   = v[g];
    }

    const float* encb = enc + ((size_t)b * TK_ + t0b) * H_;
    const int colh = lane * 4;

    // prologue: cov/mask for all 128 rows of this block + stage subtile 0
    if (tid < NS * SR) {
        cov_s[tid]  = cov[(size_t)b * TK_ + t0b + tid];
        mask_s[tid] = mask[(size_t)b * TK_ + t0b + tid];
    }
    #pragma unroll
    for (int it = 0; it < 8; ++it) {
        int row = it * 4 + w;
        float4 f = *(const float4*)(encb + (size_t)row * H_ + colh);
        bf16x4 q; q[0]=(bf16_t)f.x; q[1]=(bf16_t)f.y; q[2]=(bf16_t)f.z; q[3]=(bf16_t)f.w;
        *(bf16x4*)(&As[0][row * 264 + colh]) = q;
    }
    __syncthreads();

    float c0=0.f, c1=0.f, c2=0.f, c3=0.f;   // ctx acc: rows w*8..w*8+7, h=colh..+3
    float d_tot = 0.f;
    int p = 0;

    for (int s = 0; s < NS; ++s) {
        const int tl0 = s * SR;                 // block-local row base

        // B: GEMM on As[p] — wave w covers g in [w*64, w*64+64)
        floatx4 acc[2][4];
        #pragma unroll
        for (int mi = 0; mi < 2; ++mi)
            #pragma unroll
            for (int ni = 0; ni < 4; ++ni)
                acc[mi][ni] = (floatx4){0.f, 0.f, 0.f, 0.f};

        #pragma unroll
        for (int ks = 0; ks < 8; ++ks) {
            const int k = ks * 32 + l4 * 8;
            bf16x8 a0 = *(const bf16x8*)(&As[p][(     l15) * 264 + k]);
            bf16x8 a1 = *(const bf16x8*)(&As[p][(16 + l15) * 264 + k]);
            bf16x8 bq[4];
            #pragma unroll
            for (int ni = 0; ni < 4; ++ni)
                bq[ni] = *(const bf16x8*)(We_bf + (size_t)(wbase + ni * 16 + l15) * H_ + k);
            #pragma unroll
            for (int ni = 0; ni < 4; ++ni) {
                acc[0][ni] = __builtin_amdgcn_mfma_f32_16x16x32_bf16(a0, bq[ni], acc[0][ni], 0, 0, 0);
                acc[1][ni] = __builtin_amdgcn_mfma_f32_16x16x32_bf16(a1, bq[ni], acc[1][ni], 0, 0, 0);
            }
        }

        // S: stage next subtile into As[p^1]. With ~170 regs/wave the compiler
        // may hoist the 8 loads above the MFMAs — now free, not a spill.
        if (s < NS - 1) {
            const float* nb = encb + (size_t)(s + 1) * SR * H_;
            #pragma unroll
            for (int it = 0; it < 8; ++it) {
                int row = it * 4 + w;
                float4 f = *(const float4*)(nb + (size_t)row * H_ + colh);
                bf16x4 q; q[0]=(bf16_t)f.x; q[1]=(bf16_t)f.y; q[2]=(bf16_t)f.z; q[3]=(bf16_t)f.w;
                *(bf16x4*)(&As[p ^ 1][row * 264 + colh]) = q;
            }
        }

        // C: scores. C-layout: col(g)=lane&15, row(t)=(lane>>4)*4+reg
        #pragma unroll
        for (int mi = 0; mi < 2; ++mi) {
            #pragma unroll
            for (int r = 0; r < 4; ++r) {
                int tl = mi * 16 + l4 * 4 + r;
                float cv = cov_s[tl0 + tl];
                float ssum = 0.f;
                #pragma unroll
                for (int ni = 0; ni < 4; ++ni) {
                    float af = acc[mi][ni][r] + decv[ni] + cv * wcv[ni];
                    ssum += tanh_fast(af) * vv[ni];
                }
                ssum += __shfl_xor(ssum, 1, 64);
                ssum += __shfl_xor(ssum, 2, 64);
                ssum += __shfl_xor(ssum, 4, 64);
                ssum += __shfl_xor(ssum, 8, 64);
                if (l15 == 0) sp[w][tl] = ssum;
            }
        }
        __syncthreads();   // mid: sp visible; As[p^1] staged

        // E: wave w owns rows w*8..w*8+7 — ctx acc + attn write + denom
        #pragma unroll
        for (int j = 0; j < 8; ++j) {
            int t = w * 8 + j;
            float sc = sp[0][t] + sp[1][t] + sp[2][t] + sp[3][t];
            float wv = __builtin_amdgcn_exp2f(sc * 1.4426950408889634f)
                       * mask_s[tl0 + t];
            if (lane == 0) {
                attn_out[(size_t)b * TK_ + t0b + tl0 + t] = wv;
                d_tot += wv;
            }
            bf16x4 q = *(const bf16x4*)(&As[p][t * 264 + colh]);
            c0 += wv * (float)q[0];
            c1 += wv * (float)q[1];
            c2 += wv * (float)q[2];
            c3 += wv * (float)q[3];
        }
        __syncthreads();   // end: sp free for rewrite; As[p] free for re-stage
        p ^= 1;
    }

    // final reduces: d across waves (reuse sp), ctx across waves (ctxp)
    if (lane == 0) sp[w][0] = d_tot;
    *(float4*)(&ctxp[w][colh]) = (float4){c0, c1, c2, c3};
    __syncthreads();
    float sctx = ctxp[0][tid] + ctxp[1][tid] + ctxp[2][tid] + ctxp[3][tid];
    ctx_part[((size_t)b * NBX + xb) * H_ + tid] = sctx;
    if (tid == 0) D_part[b * NBX + xb] = sp[0][0] + sp[1][0] + sp[2][0] + sp[3][0];
}

// ---------------- finalize: reduce partials, write attn / new_cov / c_t ------
__global__ void finalize_kernel(const float* __restrict__ cov,
                                const float* __restrict__ ctx_part,
                                const float* __restrict__ D_part,
                                float* __restrict__ out) {
    int b = blockIdx.y, chunk = blockIdx.x, tid = threadIdx.x;
    int lane = tid & 63;

    // every wave redundantly reduces the 64 denominator partials (no barrier)
    float dv = D_part[b * NBX + lane];
    dv += __shfl_xor(dv, 1, 64);  dv += __shfl_xor(dv, 2, 64);
    dv += __shfl_xor(dv, 4, 64);  dv += __shfl_xor(dv, 8, 64);
    dv += __shfl_xor(dv, 16, 64); dv += __shfl_xor(dv, 32, 64);
    float invD = 1.0f / dv;

    int idx = chunk * 256 + tid;
    size_t gi = (size_t)b * TK_ + idx;
    float* attn = out + 8192;
    float* ncov = out + 8192 + (size_t)B_ * TK_;
    float a = attn[gi] * invD;
    attn[gi] = a;
    float nc = cov[gi] + a;
    ncov[gi] = fminf(fmaxf(nc, 0.f), 1.f);

    if (chunk == 0) {
        const float* cp = ctx_part + (size_t)b * NBX * H_ + tid;
        float s = 0.f;
        #pragma unroll
        for (int x = 0; x < NBX; ++x) s += cp[(size_t)x * H_];
        out[b * 256 + tid] = s * invD;
    }
}

extern "C" void kernel_launch(void* const* d_in, const int* in_sizes, int n_in,
                              void* d_out, int out_size, void* d_ws, size_t ws_size,
                              hipStream_t stream) {
    const float* s_t_hat = (const float*)d_in[0];
    const float* enc     = (const float*)d_in[1];
    const float* mask    = (const float*)d_in[2];
    const float* cov     = (const float*)d_in[3];
    // d_in[4] = attn_dist_node_to_token: unused by reference
    const float* We      = (const float*)d_in[5];
    const float* Wd      = (const float*)d_in[6];
    const float* bd      = (const float*)d_in[7];
    const float* wc      = (const float*)d_in[8];
    const float* v       = (const float*)d_in[9];
    float* out = (float*)d_out;

    char* ws = (char*)d_ws;
    bf16_t* We_bf    = (bf16_t*)ws;                          // 131072 B
    float*  dec_ws   = (float*)(ws + 131072);                // 32768 B
    float*  D_part   = (float*)(ws + 131072 + 32768);        // 32*64*4 = 8192 B
    float*  ctx_part = (float*)(ws + 131072 + 32768 + 8192); // 32*64*256*4 = 2 MiB

    prep_kernel<<<256, 256, 0, stream>>>(s_t_hat, We, Wd, bd, We_bf, dec_ws);
    attn_main<<<dim3(NBX, 32), 256, 0, stream>>>(enc, mask, cov, wc, v, We_bf,
                                                 dec_ws, ctx_part, D_part, out + 8192);
    finalize_kernel<<<dim3(32, 32), 256, 0, stream>>>(cov, ctx_part, D_part, out);
}

// Round 6
// 406.942 us; speedup vs baseline: 1.2990x; 1.2990x over previous
//
#include <hip/hip_runtime.h>

#define B_  32
#define TK_ 8192
#define H_  256
#define SR  32    // subtile rows
#define NS  16    // subtiles per block
#define NBX 16    // blocks along t (NBX*NS*SR = 8192) -> 512 blocks, 2/CU, persistent

typedef __bf16 bf16_t;
typedef __bf16 bf16x8 __attribute__((ext_vector_type(8)));
typedef float  floatx4 __attribute__((ext_vector_type(4)));

__device__ __forceinline__ float tanh_fast(float x) {
    // tanh(x) = 1 - 2/(1+e^{2x});  e^{2x} = exp2(2*log2(e)*x)
    float e = __builtin_amdgcn_exp2f(x * 2.885390081777927f);
    return 1.0f - 2.0f * __builtin_amdgcn_rcpf(e + 1.0f);
}

// ---------------- prep: convert We->bf16, compute dec_fea ---------------------
__global__ void prep_kernel(const float* __restrict__ s_t_hat,
                            const float* __restrict__ We,
                            const float* __restrict__ Wd,
                            const float* __restrict__ bd,
                            bf16_t* __restrict__ We_bf,
                            float* __restrict__ dec_ws) {
    int tid = threadIdx.x, blk = blockIdx.x;
    int gid = blk * 256 + tid;              // grid = 256 blocks -> 65536 threads
    We_bf[gid] = (bf16_t)We[gid];           // H*H = 65536 exactly

    if (blk >= 32 && blk < 160) {           // 32768 threads: 4 per (b,i)
        int idx  = (blk - 32) * 256 + tid;
        int pair = idx >> 2, q = idx & 3;
        int b = pair >> 8, i = pair & 255;
        const float4* sp = (const float4*)(s_t_hat + b * 2 * H_ + q * 128);
        const float4* wp = (const float4*)(Wd + (size_t)i * 2 * H_ + q * 128);
        float sum = 0.f;
        #pragma unroll 8
        for (int ii = 0; ii < 32; ++ii) {
            float4 a = sp[ii], w = wp[ii];
            sum += a.x * w.x + a.y * w.y + a.z * w.z + a.w * w.w;
        }
        sum += __shfl_xor(sum, 1, 64);
        sum += __shfl_xor(sum, 2, 64);
        if (q == 0) dec_ws[pair] = sum + bd[i];
    }
}

// ---------------- main fused pass ---------------------------------------------
// Staging via global_load_lds (zero VGPR cost -> no spill possible), raw f32 in
// LDS, XOR-swizzled via pre-swizzled global source (both-sides rule). 2-phase
// pipeline: issue next subtile's DMA, compute current, __syncthreads() drains
// vmcnt while other block's compute covers. We-slice preloaded to 128 VGPRs.
__global__ __launch_bounds__(256, 2) void attn_main(
    const float* __restrict__ enc,
    const float* __restrict__ mask,
    const float* __restrict__ cov,
    const float* __restrict__ wc,
    const float* __restrict__ v,
    const bf16_t* __restrict__ We_bf,
    const float* __restrict__ dec_ws,
    float* __restrict__ ctx_part,   // [B][NBX][H]
    float* __restrict__ D_part,     // [B][NBX]
    float* __restrict__ attn_out) {

    __shared__ __align__(16) float As32[2][SR * 256];  // ping-pong, 65536 B
    __shared__ float sp[4][SR];                        // per-wave score partials
    __shared__ float ctxp[4][256];                     // final ctx reduce
    __shared__ float cov_s[NS * SR], mask_s[NS * SR];  // whole-block cov/mask (4 KB)

    const int tid  = threadIdx.x;
    const int b    = blockIdx.y;
    const int xb   = blockIdx.x;
    const int lane = tid & 63, w = tid >> 6;
    const int l15  = lane & 15, l4 = lane >> 4;
    const int t0b  = xb * (NS * SR);

    const int wbase = w * 64;
    // persistent per-thread constants
    float decv[4], wcv[4], vv[4];
    #pragma unroll
    for (int ni = 0; ni < 4; ++ni) {
        int g = wbase + ni * 16 + l15;
        decv[ni] = dec_ws[b * H_ + g];
        wcv[ni]  = wc[g];
        vv[ni]   = v[g];
    }
    // preload this wave's whole We slice: 4 ni x 8 ks x 16B = 128 VGPRs.
    // Reused by all 16 subtiles; removes all L2 loads from the GEMM loop.
    bf16x8 bq[4][8];
    #pragma unroll
    for (int ni = 0; ni < 4; ++ni)
        #pragma unroll
        for (int ks = 0; ks < 8; ++ks)
            bq[ni][ks] = *(const bf16x8*)(We_bf + (size_t)(wbase + ni * 16 + l15) * H_
                                          + ks * 32 + l4 * 8);

    const float* encb = enc + ((size_t)b * TK_ + t0b) * H_;

    // cov/mask for all 512 rows of this block
    cov_s[tid]        = cov[(size_t)b * TK_ + t0b + tid];
    cov_s[tid + 256]  = cov[(size_t)b * TK_ + t0b + tid + 256];
    mask_s[tid]       = mask[(size_t)b * TK_ + t0b + tid];
    mask_s[tid + 256] = mask[(size_t)b * TK_ + t0b + tid + 256];

    // stage subtile s into buffer buf: per wave 8 rows, 1 KB each, DMA direct
    // to LDS. Global source pre-swizzled so LDS unit u holds enc unit u^(row&7)
    // (16B units) -> conflict-free swizzled reads below.
    #define STAGE(buf, sidx)                                                     \
    {                                                                            \
        const float* nb_ = encb + (size_t)(sidx) * SR * H_;                      \
        _Pragma("unroll")                                                        \
        for (int it_ = 0; it_ < 8; ++it_) {                                      \
            int row_ = it_ * 4 + w;                                              \
            const float* g_ = nb_ + (size_t)row_ * H_                            \
                              + ((lane * 4) ^ ((row_ & 7) << 2));                \
            __builtin_amdgcn_global_load_lds(                                    \
                (const __attribute__((address_space(1))) void*)g_,               \
                (__attribute__((address_space(3))) void*)&As32[buf][row_ * 256], \
                16, 0, 0);                                                       \
        }                                                                        \
    }

    STAGE(0, 0)
    __syncthreads();   // drains vmcnt: subtile 0 resident

    float c0 = 0.f, c1 = 0.f, c2 = 0.f, c3 = 0.f;
    float d_tot = 0.f;
    int p = 0;

    for (int s = 0; s < NS; ++s) {
        const int tl0 = s * SR;

        // A: issue next subtile's DMA — in flight across GEMM+scores
        if (s < NS - 1) STAGE(p ^ 1, s + 1)

        // B: GEMM on As32[p]; read f32 swizzled, cvt to bf16 fragments
        const float* Ap = &As32[p][0];
        floatx4 acc[2][4];
        #pragma unroll
        for (int mi = 0; mi < 2; ++mi)
            #pragma unroll
            for (int ni = 0; ni < 4; ++ni)
                acc[mi][ni] = (floatx4){0.f, 0.f, 0.f, 0.f};

        #pragma unroll
        for (int ks = 0; ks < 8; ++ks) {
            const int rb = ks * 128 + l4 * 32;
            bf16x8 av[2];
            #pragma unroll
            for (int mi = 0; mi < 2; ++mi) {
                int row = mi * 16 + l15;
                int sw  = (row & 7) << 4;
                floatx4 f0 = *(const floatx4*)((const char*)(Ap + row * 256) + ((rb     ) ^ sw));
                floatx4 f1 = *(const floatx4*)((const char*)(Ap + row * 256) + ((rb + 16) ^ sw));
                bf16x8 a_;
                a_[0] = (bf16_t)f0.x; a_[1] = (bf16_t)f0.y;
                a_[2] = (bf16_t)f0.z; a_[3] = (bf16_t)f0.w;
                a_[4] = (bf16_t)f1.x; a_[5] = (bf16_t)f1.y;
                a_[6] = (bf16_t)f1.z; a_[7] = (bf16_t)f1.w;
                av[mi] = a_;
            }
            #pragma unroll
            for (int ni = 0; ni < 4; ++ni) {
                acc[0][ni] = __builtin_amdgcn_mfma_f32_16x16x32_bf16(av[0], bq[ni][ks], acc[0][ni], 0, 0, 0);
                acc[1][ni] = __builtin_amdgcn_mfma_f32_16x16x32_bf16(av[1], bq[ni][ks], acc[1][ni], 0, 0, 0);
            }
        }

        // C: scores. C-layout: col(g)=lane&15, row(t)=(lane>>4)*4+reg
        #pragma unroll
        for (int mi = 0; mi < 2; ++mi) {
            #pragma unroll
            for (int r = 0; r < 4; ++r) {
                int tl = mi * 16 + l4 * 4 + r;
                float cv = cov_s[tl0 + tl];
                float ssum = 0.f;
                #pragma unroll
                for (int ni = 0; ni < 4; ++ni) {
                    float af = acc[mi][ni][r] + decv[ni] + cv * wcv[ni];
                    ssum += tanh_fast(af) * vv[ni];
                }
                ssum += __shfl_xor(ssum, 1, 64);
                ssum += __shfl_xor(ssum, 2, 64);
                ssum += __shfl_xor(ssum, 4, 64);
                ssum += __shfl_xor(ssum, 8, 64);
                if (l15 == 0) sp[w][tl] = ssum;
            }
        }
        __syncthreads();   // sp visible; vmcnt drained -> As32[p^1] resident

        // E: wave w owns rows w*8..w*8+7 — ctx acc (f32!) + attn write + denom
        #pragma unroll
        for (int j = 0; j < 8; ++j) {
            int t = w * 8 + j;
            float sc = sp[0][t] + sp[1][t] + sp[2][t] + sp[3][t];
            float wv = __builtin_amdgcn_exp2f(sc * 1.4426950408889634f)
                       * mask_s[tl0 + t];
            if (lane == 0) {
                attn_out[(size_t)b * TK_ + t0b + tl0 + t] = wv;
                d_tot += wv;
            }
            floatx4 q = *(const floatx4*)((const char*)(Ap + t * 256)
                                          + ((lane * 16) ^ ((t & 7) << 4)));
            c0 += wv * q.x;
            c1 += wv * q.y;
            c2 += wv * q.z;
            c3 += wv * q.w;
        }
        __syncthreads();   // E done reading As32[p]; safe to re-stage into it
        p ^= 1;
    }

    // final reduces: d across waves (reuse sp), ctx across waves (ctxp)
    if (lane == 0) sp[w][0] = d_tot;
    {
        int h0 = lane * 4;
        ctxp[w][h0 + 0] = c0; ctxp[w][h0 + 1] = c1;
        ctxp[w][h0 + 2] = c2; ctxp[w][h0 + 3] = c3;
    }
    __syncthreads();
    float sctx = ctxp[0][tid] + ctxp[1][tid] + ctxp[2][tid] + ctxp[3][tid];
    ctx_part[((size_t)b * NBX + xb) * H_ + tid] = sctx;
    if (tid == 0) D_part[b * NBX + xb] = sp[0][0] + sp[1][0] + sp[2][0] + sp[3][0];
}

// ---------------- finalize: reduce partials, write attn / new_cov / c_t ------
__global__ void finalize_kernel(const float* __restrict__ cov,
                                const float* __restrict__ ctx_part,
                                const float* __restrict__ D_part,
                                float* __restrict__ out) {
    int b = blockIdx.y, chunk = blockIdx.x, tid = threadIdx.x;
    int lane = tid & 63;

    // every wave redundantly reduces the 16 denominator partials (no barrier)
    float dv = (lane < NBX) ? D_part[b * NBX + lane] : 0.f;
    dv += __shfl_xor(dv, 1, 64);  dv += __shfl_xor(dv, 2, 64);
    dv += __shfl_xor(dv, 4, 64);  dv += __shfl_xor(dv, 8, 64);
    dv += __shfl_xor(dv, 16, 64); dv += __shfl_xor(dv, 32, 64);
    float invD = 1.0f / dv;

    int idx = chunk * 256 + tid;
    size_t gi = (size_t)b * TK_ + idx;
    float* attn = out + 8192;
    float* ncov = out + 8192 + (size_t)B_ * TK_;
    float a = attn[gi] * invD;
    attn[gi] = a;
    float nc = cov[gi] + a;
    ncov[gi] = fminf(fmaxf(nc, 0.f), 1.f);

    if (chunk == 0) {
        const float* cp = ctx_part + (size_t)b * NBX * H_ + tid;
        float s = 0.f;
        #pragma unroll
        for (int x = 0; x < NBX; ++x) s += cp[(size_t)x * H_];
        out[b * 256 + tid] = s * invD;
    }
}

extern "C" void kernel_launch(void* const* d_in, const int* in_sizes, int n_in,
                              void* d_out, int out_size, void* d_ws, size_t ws_size,
                              hipStream_t stream) {
    const float* s_t_hat = (const float*)d_in[0];
    const float* enc     = (const float*)d_in[1];
    const float* mask    = (const float*)d_in[2];
    const float* cov     = (const float*)d_in[3];
    // d_in[4] = attn_dist_node_to_token: unused by reference
    const float* We      = (const float*)d_in[5];
    const float* Wd      = (const float*)d_in[6];
    const float* bd      = (const float*)d_in[7];
    const float* wc      = (const float*)d_in[8];
    const float* v       = (const float*)d_in[9];
    float* out = (float*)d_out;

    char* ws = (char*)d_ws;
    bf16_t* We_bf    = (bf16_t*)ws;                          // 131072 B
    float*  dec_ws   = (float*)(ws + 131072);                // 32768 B
    float*  D_part   = (float*)(ws + 131072 + 32768);        // 32*16*4 = 2048 B
    float*  ctx_part = (float*)(ws + 131072 + 32768 + 2048); // 32*16*256*4 = 512 KiB

    prep_kernel<<<256, 256, 0, stream>>>(s_t_hat, We, Wd, bd, We_bf, dec_ws);
    attn_main<<<dim3(NBX, 32), 256, 0, stream>>>(enc, mask, cov, wc, v, We_bf,
                                                 dec_ws, ctx_part, D_part, out + 8192);
    finalize_kernel<<<dim3(32, 32), 256, 0, stream>>>(cov, ctx_part, D_part, out);
}